// Round 8
// baseline (249.226 us; speedup 1.0000x reference)
//
#include <hip/hip_runtime.h>
#include <hip/hip_bf16.h>
#include <stdint.h>

// ---------------------------------------------------------------------------
// LayerNormLSTMCell: B=4096, I=H=1024, 4H=4096
//  hi = LN(input @ w_i2h + b_i2h; g_i2h, be_i2h)        [B,4H]
//  hh = LN(h_prev @ w_h2h + b_h2h; g_h2h, be_h2h)       [B,4H]
//  i,f,u,o = split(hi+hh, 4)
//  c = LN(c_prev*sigm(f+1) + tanh(u)*sigm(i); g_c,be_c) [B,H]
//  h = sigm(o)*tanh(c)
// LN: mean, UNBIASED std (ddof=1), divide by (std + 1e-6)
// ---------------------------------------------------------------------------

#define BDIM 4096
#define KDIM 1024
#define NDIM 4096
#define EPSV 1e-6f

typedef float f32x4 __attribute__((ext_vector_type(4)));
typedef __bf16 bf16x8 __attribute__((ext_vector_type(8)));
typedef unsigned short u16x8 __attribute__((ext_vector_type(8)));

__device__ inline unsigned short f2bf(float f) {
    unsigned u = __builtin_bit_cast(unsigned, f);
    u += 0x7FFFu + ((u >> 16) & 1u);   // round-to-nearest-even
    return (unsigned short)(u >> 16);
}
__device__ inline float bf2f(unsigned short u) {
    return __builtin_bit_cast(float, (unsigned)u << 16);
}
__device__ inline float sigm(float x) {
    return 1.0f / (1.0f + __expf(-x));
}
__device__ inline float ftanh(float x) {
    return 1.0f - 2.0f / (__expf(2.0f * x) + 1.0f);
}

// async global->LDS, 16B per lane. lds ptr must be wave-uniform.
__device__ inline void async16(const unsigned short* g, unsigned short* lds) {
    __builtin_amdgcn_global_load_lds(
        (const __attribute__((address_space(1))) void*)g,
        (__attribute__((address_space(3))) void*)lds,
        16, 0, 0);
}

// raw workgroup barrier with compiler memory fence (does NOT drain vmcnt).
__device__ inline void bar() {
    asm volatile("" ::: "memory");
    __builtin_amdgcn_s_barrier();
    asm volatile("" ::: "memory");
}
#define WAIT_LGKM0() asm volatile("s_waitcnt lgkmcnt(0)" ::: "memory")
#define WAIT_VM0()   asm volatile("s_waitcnt vmcnt(0)" ::: "memory")
#define MFMA(a, b, c) __builtin_amdgcn_mfma_f32_16x16x32_bf16((a), (b), (c), 0, 0, 0)

// ---------------------------------------------------------------------------
// prep: z=0/1 cast input/h_prev f32->bf16 (8 elem/thread, 16B stores)
//       z=2/3 transpose+cast w f32 [1024][4096] -> bf16 [4096][1024]
// ---------------------------------------------------------------------------
__global__ __launch_bounds__(256) void prep(
    const float* __restrict__ in0, unsigned short* __restrict__ o0,
    const float* __restrict__ in1, unsigned short* __restrict__ o1,
    const float* __restrict__ w0, unsigned short* __restrict__ w0T,
    const float* __restrict__ w1, unsigned short* __restrict__ w1T)
{
    __shared__ float tile[64][65];
    const int z = blockIdx.z, tid = threadIdx.x;
    if (z < 2) {
        const float* src = z ? in1 : in0;
        unsigned short* dst = z ? o1 : o0;
        int i = (blockIdx.x * 256 + tid) * 8;
        float4 a = *(const float4*)(src + i);
        float4 b = *(const float4*)(src + i + 4);
        u16x8 v;
        v[0] = f2bf(a.x); v[1] = f2bf(a.y); v[2] = f2bf(a.z); v[3] = f2bf(a.w);
        v[4] = f2bf(b.x); v[5] = f2bf(b.y); v[6] = f2bf(b.z); v[7] = f2bf(b.w);
        *(u16x8*)(dst + i) = v;
        return;
    }
    const int bx = blockIdx.x;
    if (bx >= (NDIM / 64) * (KDIM / 64)) return;
    const float* src = (z == 3) ? w1 : w0;
    unsigned short* dst = (z == 3) ? w1T : w0T;
    const int c0 = (bx & (NDIM / 64 - 1)) * 64;   // col in [0,4096)
    const int r0 = (bx >> 6) * 64;                // row in [0,1024)
    const int tx = tid & 63, ty = tid >> 6;       // 64 x 4
    #pragma unroll
    for (int i = 0; i < 64; i += 4)
        tile[ty + i][tx] = src[(size_t)(r0 + ty + i) * NDIM + c0 + tx];
    __syncthreads();
    #pragma unroll
    for (int p = 0; p < 2; ++p) {
        int c = p * 32 + (tid >> 3);
        int rs = (tid & 7) * 8;
        u16x8 v;
        #pragma unroll
        for (int j = 0; j < 8; ++j) v[j] = f2bf(tile[rs + j][c]);
        *(u16x8*)(dst + (size_t)(c0 + c) * KDIM + r0 + rs) = v;
    }
}

// ---------------------------------------------------------------------------
// GEMM: C[m][n] = sum_k A[m][k] * Bt[n][k] + bias[n]   (bf16 in, bf16 out)
// M=4096 N=4096 K=1024.
//
// R7: RACE-HARDENED pipeline. R6 (R4's oldest-N counted-vmcnt conveyor +
// XCD swizzle) FAILED the replay tripwire intermittently: the counted
// waits' correctness depended on oldest-N precision of the in-loop vmem
// population -- fragile to compiler-placed vmem ops and exposed by the
// swizzle's mixed L2/HBM completion timing. Fix: staging restructured so
// the ONLY vm wait is an EXACT full drain:
//   P1(t): ds_read AL,BL; issue ALL 8 stage ops for tile t+1 (one burst);
//          bar; lgkm0; MFMA AL*BL; bar
//   P2(t): ds_read BH; bar; lgkm0; MFMA AL*BH; bar
//   P3(t): ds_read AH; bar; lgkm0; MFMA AH*BH; bar
//   P4(t): MFMA AH*BL; WAIT_VM0 (exact); bar
// Loads issued at P1 retain ~3.5 phases (~500-600cy) of MFMA/ds cover
// before the P4 drain (T4's latency-hiding intent preserved; the R2
// regression was vm(0) with ~1 phase cover). vm(0) is correct regardless
// of any extra vmem ops -> the oldest-N race class is eliminated.
//
// RAW: tile t's reads covered by P4(t-1)'s vm(0) (every wave) + barrier.
// WAR: stage into nxt at P1(t) is two barriers after the last reads of
// that buffer (P3(t-1) ds_reads, drained by lgkm0 before P3-end barrier).
//
// XCD-bijective swizzle kept (R6-validated: FETCH 74->50.3MB = analytic
// L2-sharing floor of 48MB). ds_read front-load NOT reintroduced (R6
// measured it -12us: VGPR 116->128).
//
// Data path: staging rows XOR-swizzle global k-seg (sseg=(lane&7)^(row&7)),
// LDS linear; fragment reads phys seg=(s*4+q)^r7 (ZERO bank conflicts,
// verified R2/R4/R6); C/D D[row=(lane>>4)*4+r][col=lane&15].
// ---------------------------------------------------------------------------
__global__ __launch_bounds__(512, 2) void gemm_bias_bf16(
    const unsigned short* __restrict__ A0, const unsigned short* __restrict__ B0,
    const float* __restrict__ bias0, unsigned short* __restrict__ C0,
    const unsigned short* __restrict__ A1, const unsigned short* __restrict__ B1,
    const float* __restrict__ bias1, unsigned short* __restrict__ C1)
{
    const unsigned short* A  = blockIdx.z ? A1 : A0;
    const unsigned short* Bt = blockIdx.z ? B1 : B0;
    const float* bias        = blockIdx.z ? bias1 : bias0;
    unsigned short* C        = blockIdx.z ? C1 : C0;

    __shared__ __align__(16) unsigned short Als[2 * 256 * 64];   // 64 KB
    __shared__ __align__(16) unsigned short Bls[2 * 256 * 64];   // 64 KB
    const int TILE = 256 * 64;

    const int tid  = threadIdx.x;
    const int wid  = tid >> 6;
    const int lane = tid & 63;

    // ---- XCD-bijective swizzle (R6-validated): b%8 ~ XCD; each XCD owns a
    // 4bm x 8bn chunk (32 blocks, co-resident at 1 blk/CU) ----
    const int b   = blockIdx.x;          // 0..255
    const int xcd = b & 7, idx = b >> 3; // idx 0..31
    const int bm  = (xcd >> 1) * 4 + (idx & 3);    // 0..15
    const int bn  = (xcd & 1) * 8 + (idx >> 2);    // 0..15

    const int wr = wid >> 2;        // wave row: rows wr*128
    const int wc = wid & 3;         // wave col: cols wc*64

    f32x4 acc[8][4] = {};

    // ---- staging bases: chunk = 8 rows x 64 cols (1KB) per async16;
    // row = R + (lane>>3); global k-seg XOR-swizzled (row&7 = lane>>3) ----
    const int sseg = (lane & 7) ^ (lane >> 3);
    const unsigned short* AsrcB = A + ((size_t)(bm * 256) + (lane >> 3)) * KDIM + sseg * 8;
    const unsigned short* BsrcB = Bt + ((size_t)(bn * 256) + (lane >> 3)) * KDIM + sseg * 8;

    // per-wave chunk rows (coverage: A rows wid*8+{0,64,128,192};
    // B rows: waves*4 chunks of 8 spanning [0,256))
    const int aR0 = wid * 8,       aR1 = 64 + wid * 8;
    const int aR2 = 128 + wid * 8, aR3 = 192 + wid * 8;
    const int bB  = (wid >> 1) * 64 + (wid & 1) * 16;   // base of wave's B region
    const int bR0 = bB, bR1 = bB + 8, bR2 = bB + 32, bR3 = bB + 40;

    auto stA = [&](int R, int k, int buf) {
        async16(AsrcB + (size_t)R * KDIM + k, Als + buf + R * 64);
    };
    auto stB = [&](int R, int k, int buf) {
        async16(BsrcB + (size_t)R * KDIM + k, Bls + buf + R * 64);
    };
    auto stage_all = [&](int k, int buf) {
        stA(aR0, k, buf); stA(aR1, k, buf); stA(aR2, k, buf); stA(aR3, k, buf);
        stB(bR0, k, buf); stB(bR1, k, buf); stB(bR2, k, buf); stB(bR3, k, buf);
    };

    // ---- fragment addressing (16x16x32, conflict-free) ----
    const int frow = lane & 15;
    const int r7   = lane & 7;
    const int ph0  = ((lane >> 4) ^ r7) * 8;   // k-seg s=0 (phys, elements)
    const int ph1v = ph0 ^ 32;                 // k-seg s=1 (s*4 flips bit 2)
    int aOff[8], bOff[4];
    #pragma unroll
    for (int mi = 0; mi < 8; ++mi) aOff[mi] = (wr * 128 + mi * 16 + frow) * 64;
    #pragma unroll
    for (int ni = 0; ni < 4; ++ni) bOff[ni] = (wc * 64 + ni * 16 + frow) * 64;

    // ---- prologue: stage K-tile 0 into buffer 0, exact drain, sync ----
    stage_all(0, 0);
    WAIT_VM0();
    bar();

    bf16x8 aL[4][2], aH[4][2], bL[2][2], bH[2][2];

    for (int t = 0; t < 16; ++t) {
        const int cur = (t & 1) * TILE;
        const int nxt = cur ^ TILE;
        const int k1  = t * 64 + 64;       // next tile's k offset
        const bool pf = (t < 15);

        // ===== P1: read AL,BL; burst-issue ALL of tile t+1; MFMA AL*BL =====
        #pragma unroll
        for (int mi = 0; mi < 4; ++mi) {
            aL[mi][0] = *(const bf16x8*)&Als[cur + aOff[mi] + ph0];
            aL[mi][1] = *(const bf16x8*)&Als[cur + aOff[mi] + ph1v];
        }
        #pragma unroll
        for (int ni = 0; ni < 2; ++ni) {
            bL[ni][0] = *(const bf16x8*)&Bls[cur + bOff[ni] + ph0];
            bL[ni][1] = *(const bf16x8*)&Bls[cur + bOff[ni] + ph1v];
        }
        if (pf) stage_all(k1, nxt);
        bar();
        WAIT_LGKM0();
        __builtin_amdgcn_s_setprio(1);
        #pragma unroll
        for (int mi = 0; mi < 4; ++mi)
            #pragma unroll
            for (int ni = 0; ni < 2; ++ni) {
                acc[mi][ni] = MFMA(aL[mi][0], bL[ni][0], acc[mi][ni]);
                acc[mi][ni] = MFMA(aL[mi][1], bL[ni][1], acc[mi][ni]);
            }
        __builtin_amdgcn_s_setprio(0);
        bar();

        // ===== P2: read BH; MFMA AL*BH =====
        #pragma unroll
        for (int ni = 0; ni < 2; ++ni) {
            bH[ni][0] = *(const bf16x8*)&Bls[cur + bOff[ni + 2] + ph0];
            bH[ni][1] = *(const bf16x8*)&Bls[cur + bOff[ni + 2] + ph1v];
        }
        bar();
        WAIT_LGKM0();
        __builtin_amdgcn_s_setprio(1);
        #pragma unroll
        for (int mi = 0; mi < 4; ++mi)
            #pragma unroll
            for (int ni = 0; ni < 2; ++ni) {
                acc[mi][ni + 2] = MFMA(aL[mi][0], bH[ni][0], acc[mi][ni + 2]);
                acc[mi][ni + 2] = MFMA(aL[mi][1], bH[ni][1], acc[mi][ni + 2]);
            }
        __builtin_amdgcn_s_setprio(0);
        bar();

        // ===== P3: read AH; MFMA AH*BH =====
        #pragma unroll
        for (int mi = 0; mi < 4; ++mi) {
            aH[mi][0] = *(const bf16x8*)&Als[cur + aOff[mi + 4] + ph0];
            aH[mi][1] = *(const bf16x8*)&Als[cur + aOff[mi + 4] + ph1v];
        }
        bar();
        WAIT_LGKM0();
        __builtin_amdgcn_s_setprio(1);
        #pragma unroll
        for (int mi = 0; mi < 4; ++mi)
            #pragma unroll
            for (int ni = 0; ni < 2; ++ni) {
                acc[mi + 4][ni + 2] = MFMA(aH[mi][0], bH[ni][0], acc[mi + 4][ni + 2]);
                acc[mi + 4][ni + 2] = MFMA(aH[mi][1], bH[ni][1], acc[mi + 4][ni + 2]);
            }
        __builtin_amdgcn_s_setprio(0);
        bar();

        // ===== P4: MFMA AH*BL; EXACT drain of tile t+1's loads =====
        __builtin_amdgcn_s_setprio(1);
        #pragma unroll
        for (int mi = 0; mi < 4; ++mi)
            #pragma unroll
            for (int ni = 0; ni < 2; ++ni) {
                acc[mi + 4][ni] = MFMA(aH[mi][0], bL[ni][0], acc[mi + 4][ni]);
                acc[mi + 4][ni] = MFMA(aH[mi][1], bL[ni][1], acc[mi + 4][ni]);
            }
        __builtin_amdgcn_s_setprio(0);
        WAIT_VM0();   // exact: all of tile t+1 staged (issued 3.5 phases ago)
        bar();
    }

    // ---- epilogue: D[row=(lane>>4)*4+r][col=lane&15]
    const int rb = wr * 128 + (lane >> 4) * 4;
    const int cb = wc * 64 + (lane & 15);
    float bv[4];
    #pragma unroll
    for (int ni = 0; ni < 4; ++ni) bv[ni] = bias[bn * 256 + cb + ni * 16];
    #pragma unroll
    for (int mi = 0; mi < 8; ++mi) {
        #pragma unroll
        for (int r = 0; r < 4; ++r) {
            size_t grow = (size_t)(bm * 256 + rb + mi * 16 + r) * NDIM;
            #pragma unroll
            for (int ni = 0; ni < 4; ++ni)
                C[grow + bn * 256 + cb + ni * 16] = f2bf(acc[mi][ni][r] + bv[ni]);
        }
    }
}

// ---------------------------------------------------------------------------
// fused LN(hi)+LN(hh)+gates+LN(cell)+outputs. TWO rows per block:
// sub = tid>>7 selects row, t = tid&127 covers 8 cols per gate (16B loads).
// ---------------------------------------------------------------------------
__global__ __launch_bounds__(256) void ln_gates(
    const unsigned short* __restrict__ hi_pre, const unsigned short* __restrict__ hh_pre,
    const float* __restrict__ c_prev,
    const float* __restrict__ g1, const float* __restrict__ be1,
    const float* __restrict__ g2, const float* __restrict__ be2,
    const float* __restrict__ gc, const float* __restrict__ bec,
    float* __restrict__ h_out, float* __restrict__ c_out)
{
    __shared__ float sm[16];
    const int tid = threadIdx.x;
    const int sub = tid >> 7, t = tid & 127;
    const int wv = tid >> 6, lane = tid & 63;
    const int row = blockIdx.x * 2 + sub;
    const unsigned short* hir = hi_pre + (size_t)row * NDIM;
    const unsigned short* hhr = hh_pre + (size_t)row * NDIM;

    u16x8 vi[4], vh[4];
    float s1 = 0.f, ss1 = 0.f, s2 = 0.f, ss2 = 0.f;
    #pragma unroll
    for (int q = 0; q < 4; ++q) {
        int col = q * 1024 + t * 8;
        vi[q] = *(const u16x8*)(hir + col);
        vh[q] = *(const u16x8*)(hhr + col);
        #pragma unroll
        for (int j = 0; j < 8; ++j) {
            float a = bf2f(vi[q][j]), b = bf2f(vh[q][j]);
            s1 += a; ss1 += a * a; s2 += b; ss2 += b * b;
        }
    }
    #pragma unroll
    for (int off = 32; off > 0; off >>= 1) {
        s1 += __shfl_down(s1, off, 64);
        ss1 += __shfl_down(ss1, off, 64);
        s2 += __shfl_down(s2, off, 64);
        ss2 += __shfl_down(ss2, off, 64);
    }
    if (lane == 0) {
        sm[wv * 4 + 0] = s1; sm[wv * 4 + 1] = ss1;
        sm[wv * 4 + 2] = s2; sm[wv * 4 + 3] = ss2;
    }
    __syncthreads();
    const int base = sub * 8;
    float R1 = sm[base + 0] + sm[base + 4];
    float Q1 = sm[base + 1] + sm[base + 5];
    float R2 = sm[base + 2] + sm[base + 6];
    float Q2 = sm[base + 3] + sm[base + 7];

    const float n1 = (float)NDIM;
    float m1 = R1 / n1;
    float v1 = (Q1 - n1 * m1 * m1) / (n1 - 1.f);
    float r1 = 1.0f / (sqrtf(fmaxf(v1, 0.f)) + EPSV);
    float m2 = R2 / n1;
    float v2 = (Q2 - n1 * m2 * m2) / (n1 - 1.f);
    float r2 = 1.0f / (sqrtf(fmaxf(v2, 0.f)) + EPSV);

    float gate[4][8];
    #pragma unroll
    for (int q = 0; q < 4; ++q) {
        int col = q * 1024 + t * 8;
        float4 G1a = *(const float4*)(g1 + col),  G1b = *(const float4*)(g1 + col + 4);
        float4 B1a = *(const float4*)(be1 + col), B1b = *(const float4*)(be1 + col + 4);
        float4 G2a = *(const float4*)(g2 + col),  G2b = *(const float4*)(g2 + col + 4);
        float4 B2a = *(const float4*)(be2 + col), B2b = *(const float4*)(be2 + col + 4);
        float G1[8] = {G1a.x, G1a.y, G1a.z, G1a.w, G1b.x, G1b.y, G1b.z, G1b.w};
        float B1[8] = {B1a.x, B1a.y, B1a.z, B1a.w, B1b.x, B1b.y, B1b.z, B1b.w};
        float G2[8] = {G2a.x, G2a.y, G2a.z, G2a.w, G2b.x, G2b.y, G2b.z, G2b.w};
        float B2[8] = {B2a.x, B2a.y, B2a.z, B2a.w, B2b.x, B2b.y, B2b.z, B2b.w};
        #pragma unroll
        for (int j = 0; j < 8; ++j)
            gate[q][j] = G1[j] * (bf2f(vi[q][j]) - m1) * r1 + B1[j]
                       + G2[j] * (bf2f(vh[q][j]) - m2) * r2 + B2[j];
    }

    float4 cpa = *(const float4*)(c_prev + (size_t)row * 1024 + t * 8);
    float4 cpb = *(const float4*)(c_prev + (size_t)row * 1024 + t * 8 + 4);
    float cpv[8] = {cpa.x, cpa.y, cpa.z, cpa.w, cpb.x, cpb.y, cpb.z, cpb.w};
    float a[8];
    float s3 = 0.f, ss3 = 0.f;
    #pragma unroll
    for (int j = 0; j < 8; ++j) {
        a[j] = cpv[j] * sigm(gate[1][j] + 1.0f) + ftanh(gate[2][j]) * sigm(gate[0][j]);
        s3 += a[j]; ss3 += a[j] * a[j];
    }
    #pragma unroll
    for (int off = 32; off > 0; off >>= 1) {
        s3 += __shfl_down(s3, off, 64);
        ss3 += __shfl_down(ss3, off, 64);
    }
    __syncthreads();   // sm reuse
    if (lane == 0) { sm[wv * 2 + 0] = s3; sm[wv * 2 + 1] = ss3; }
    __syncthreads();
    const int b2 = sub * 4;
    float R3 = sm[b2 + 0] + sm[b2 + 2];
    float Q3 = sm[b2 + 1] + sm[b2 + 3];
    const float n3 = 1024.f;
    float m3 = R3 / n3;
    float v3 = (Q3 - n3 * m3 * m3) / (n3 - 1.f);
    float r3 = 1.0f / (sqrtf(fmaxf(v3, 0.f)) + EPSV);

    int colh = t * 8;
    float4 GCa = *(const float4*)(gc + colh),  GCb = *(const float4*)(gc + colh + 4);
    float4 BCa = *(const float4*)(bec + colh), BCb = *(const float4*)(bec + colh + 4);
    float GC[8] = {GCa.x, GCa.y, GCa.z, GCa.w, GCb.x, GCb.y, GCb.z, GCb.w};
    float BC[8] = {BCa.x, BCa.y, BCa.z, BCa.w, BCb.x, BCb.y, BCb.z, BCb.w};
    float cj[8], hj[8];
    #pragma unroll
    for (int j = 0; j < 8; ++j) {
        cj[j] = GC[j] * (a[j] - m3) * r3 + BC[j];
        hj[j] = sigm(gate[3][j]) * ftanh(cj[j]);
    }
    float4 hva = {hj[0], hj[1], hj[2], hj[3]}, hvb = {hj[4], hj[5], hj[6], hj[7]};
    float4 cva = {cj[0], cj[1], cj[2], cj[3]}, cvb = {cj[4], cj[5], cj[6], cj[7]};
    *(float4*)(h_out + (size_t)row * 1024 + colh) = hva;
    *(float4*)(h_out + (size_t)row * 1024 + colh + 4) = hvb;
    *(float4*)(c_out + (size_t)row * 1024 + colh) = cva;
    *(float4*)(c_out + (size_t)row * 1024 + colh + 4) = cvb;
}

// ---------------------------------------------------------------------------
extern "C" void kernel_launch(void* const* d_in, const int* in_sizes, int n_in,
                              void* d_out, int out_size, void* d_ws, size_t ws_size,
                              hipStream_t stream) {
    const float* input  = (const float*)d_in[0];
    const float* h_prev = (const float*)d_in[1];
    const float* c_prev = (const float*)d_in[2];
    const float* w_i2h  = (const float*)d_in[3];
    const float* b_i2h  = (const float*)d_in[4];
    const float* w_h2h  = (const float*)d_in[5];
    const float* b_h2h  = (const float*)d_in[6];
    const float* g_i2h  = (const float*)d_in[7];
    const float* be_i2h = (const float*)d_in[8];
    const float* g_h2h  = (const float*)d_in[9];
    const float* be_h2h = (const float*)d_in[10];
    const float* g_c    = (const float*)d_in[11];
    const float* be_c   = (const float*)d_in[12];

    const size_t MK = (size_t)BDIM * KDIM;       // 4M
    const size_t MN = (size_t)BDIM * NDIM;       // 16M

    unsigned short* inA    = (unsigned short*)d_ws;
    unsigned short* inH    = inA + MK;
    unsigned short* w1T    = inH + MK;           // [N][K]
    unsigned short* w2T    = w1T + MK;
    unsigned short* hi_pre = w2T + MK;           // [B][4H] bf16
    unsigned short* hh_pre = hi_pre + MN;        // total 96 MB

    float* h_out = (float*)d_out;
    float* c_out = h_out + (size_t)BDIM * 1024;

    prep<<<dim3(2048, 1, 4), 256, 0, stream>>>(
        input, inA, h_prev, inH, w_i2h, w1T, w_h2h, w2T);

    gemm_bias_bf16<<<dim3(256, 1, 2), 512, 0, stream>>>(
        inA, w1T, b_i2h, hi_pre, inH, w2T, b_h2h, hh_pre);

    ln_gates<<<2048, 256, 0, stream>>>(
        hi_pre, hh_pre, c_prev, g_i2h, be_i2h, g_h2h, be_h2h, g_c, be_c, h_out, c_out);
}

// Round 9
// 248.339 us; speedup vs baseline: 1.0036x; 1.0036x over previous
//
#include <hip/hip_runtime.h>
#include <hip/hip_bf16.h>
#include <stdint.h>

// ---------------------------------------------------------------------------
// LayerNormLSTMCell: B=4096, I=H=1024, 4H=4096
//  hi = LN(input @ w_i2h + b_i2h; g_i2h, be_i2h)        [B,4H]
//  hh = LN(h_prev @ w_h2h + b_h2h; g_h2h, be_h2h)       [B,4H]
//  i,f,u,o = split(hi+hh, 4)
//  c = LN(c_prev*sigm(f+1) + tanh(u)*sigm(i); g_c,be_c) [B,H]
//  h = sigm(o)*tanh(c)
// LN: mean, UNBIASED std (ddof=1), divide by (std + 1e-6)
// ---------------------------------------------------------------------------

#define BDIM 4096
#define KDIM 1024
#define NDIM 4096
#define EPSV 1e-6f

typedef float f32x4 __attribute__((ext_vector_type(4)));
typedef __bf16 bf16x8 __attribute__((ext_vector_type(8)));
typedef unsigned short u16x8 __attribute__((ext_vector_type(8)));

__device__ inline unsigned short f2bf(float f) {
    unsigned u = __builtin_bit_cast(unsigned, f);
    u += 0x7FFFu + ((u >> 16) & 1u);   // round-to-nearest-even
    return (unsigned short)(u >> 16);
}
__device__ inline float bf2f(unsigned short u) {
    return __builtin_bit_cast(float, (unsigned)u << 16);
}
__device__ inline float sigm(float x) {
    return 1.0f / (1.0f + __expf(-x));
}
__device__ inline float ftanh(float x) {
    return 1.0f - 2.0f / (__expf(2.0f * x) + 1.0f);
}

// async global->LDS, 16B per lane. lds ptr must be wave-uniform.
__device__ inline void async16(const unsigned short* g, unsigned short* lds) {
    __builtin_amdgcn_global_load_lds(
        (const __attribute__((address_space(1))) void*)g,
        (__attribute__((address_space(3))) void*)lds,
        16, 0, 0);
}

// raw workgroup barrier with compiler memory fence (does NOT drain vmcnt).
__device__ inline void bar() {
    asm volatile("" ::: "memory");
    __builtin_amdgcn_s_barrier();
    asm volatile("" ::: "memory");
}
#define WAIT_VM0()   asm volatile("s_waitcnt vmcnt(0)" ::: "memory")
#define MFMA(a, b, c) __builtin_amdgcn_mfma_f32_16x16x32_bf16((a), (b), (c), 0, 0, 0)

// ---------------------------------------------------------------------------
// prep: z=0/1 cast input/h_prev f32->bf16 (8 elem/thread, 16B stores)
//       z=2/3 transpose+cast w f32 [1024][4096] -> bf16 [4096][1024]
// ---------------------------------------------------------------------------
__global__ __launch_bounds__(256) void prep(
    const float* __restrict__ in0, unsigned short* __restrict__ o0,
    const float* __restrict__ in1, unsigned short* __restrict__ o1,
    const float* __restrict__ w0, unsigned short* __restrict__ w0T,
    const float* __restrict__ w1, unsigned short* __restrict__ w1T)
{
    __shared__ float tile[64][65];
    const int z = blockIdx.z, tid = threadIdx.x;
    if (z < 2) {
        const float* src = z ? in1 : in0;
        unsigned short* dst = z ? o1 : o0;
        int i = (blockIdx.x * 256 + tid) * 8;
        float4 a = *(const float4*)(src + i);
        float4 b = *(const float4*)(src + i + 4);
        u16x8 v;
        v[0] = f2bf(a.x); v[1] = f2bf(a.y); v[2] = f2bf(a.z); v[3] = f2bf(a.w);
        v[4] = f2bf(b.x); v[5] = f2bf(b.y); v[6] = f2bf(b.z); v[7] = f2bf(b.w);
        *(u16x8*)(dst + i) = v;
        return;
    }
    const int bx = blockIdx.x;
    if (bx >= (NDIM / 64) * (KDIM / 64)) return;
    const float* src = (z == 3) ? w1 : w0;
    unsigned short* dst = (z == 3) ? w1T : w0T;
    const int c0 = (bx & (NDIM / 64 - 1)) * 64;   // col in [0,4096)
    const int r0 = (bx >> 6) * 64;                // row in [0,1024)
    const int tx = tid & 63, ty = tid >> 6;       // 64 x 4
    #pragma unroll
    for (int i = 0; i < 64; i += 4)
        tile[ty + i][tx] = src[(size_t)(r0 + ty + i) * NDIM + c0 + tx];
    __syncthreads();
    #pragma unroll
    for (int p = 0; p < 2; ++p) {
        int c = p * 32 + (tid >> 3);
        int rs = (tid & 7) * 8;
        u16x8 v;
        #pragma unroll
        for (int j = 0; j < 8; ++j) v[j] = f2bf(tile[rs + j][c]);
        *(u16x8*)(dst + (size_t)(c0 + c) * KDIM + r0 + rs) = v;
    }
}

// ---------------------------------------------------------------------------
// GEMM: C[m][n] = sum_k A[m][k] * Bt[n][k] + bias[n]   (bf16 in, bf16 out)
// M=4096 N=4096 K=1024.
//
// R8: MINIMAL-SYNC tile. R7 (race-free, 8 barriers + 3 blanket lgkm0 per
// K-tile) measured 81.7us / MfmaUtil 33.8% -- the barrier-lockstep exposes
// ds_read latency every phase and the blanket lgkm0 forbids the compiler's
// precise per-operand lgkm counting. This version: ONE phase per K-tile,
// exactly one vmcnt(0) + one barrier:
//   tile t: stage_all(t+1 -> nxt)   [issued FIRST: ~full-tile cover to vm0]
//           ds_read all 24 frags from cur   [no explicit lgkm waits]
//           64 MFMA                  [compiler inserts precise lgkmcnt(N)]
//           WAIT_VM0; bar
// Hazards (only full drains -> R7's race-immunity preserved):
//   RAW cur(t): staged during t-1, behind t-1's vm0 (every wave) + barrier.
//   WAR nxt(t): nxt(t)=cur(t-1); all reads of it are behind each wave's
//     compiler lgkm waits before its t-1 MFMAs, which precede the t-1
//     barrier. Within a tile, stage(nxt) vs ds_read(cur) are disjoint bufs.
// Flagged risk: compiler may hoist all frag reads -> VGPR up to ~244.
// If profile shows 256+scratch, pin a 2-phase split next round.
//
// XCD-bijective swizzle kept (validated: FETCH 74->49.3MB = L2-sharing
// floor). Data path: staging rows XOR-swizzle global k-seg
// (sseg=(lane&7)^(row&7)), LDS linear; fragment reads phys seg=(s*4+q)^r7
// (ZERO bank conflicts, verified R2/R4/R6/R7);
// C/D D[row=(lane>>4)*4+r][col=lane&15].
// ---------------------------------------------------------------------------
__global__ __launch_bounds__(512, 2) void gemm_bias_bf16(
    const unsigned short* __restrict__ A0, const unsigned short* __restrict__ B0,
    const float* __restrict__ bias0, unsigned short* __restrict__ C0,
    const unsigned short* __restrict__ A1, const unsigned short* __restrict__ B1,
    const float* __restrict__ bias1, unsigned short* __restrict__ C1)
{
    const unsigned short* A  = blockIdx.z ? A1 : A0;
    const unsigned short* Bt = blockIdx.z ? B1 : B0;
    const float* bias        = blockIdx.z ? bias1 : bias0;
    unsigned short* C        = blockIdx.z ? C1 : C0;

    __shared__ __align__(16) unsigned short Als[2 * 256 * 64];   // 64 KB
    __shared__ __align__(16) unsigned short Bls[2 * 256 * 64];   // 64 KB
    const int TILE = 256 * 64;

    const int tid  = threadIdx.x;
    const int wid  = tid >> 6;
    const int lane = tid & 63;

    // ---- XCD-bijective swizzle: b%8 ~ XCD; each XCD owns a 4bm x 8bn
    // chunk (32 blocks, co-resident at 1 blk/CU) ----
    const int b   = blockIdx.x;          // 0..255
    const int xcd = b & 7, idx = b >> 3; // idx 0..31
    const int bm  = (xcd >> 1) * 4 + (idx & 3);    // 0..15
    const int bn  = (xcd & 1) * 8 + (idx >> 2);    // 0..15

    const int wr = wid >> 2;        // wave row: rows wr*128
    const int wc = wid & 3;         // wave col: cols wc*64

    f32x4 acc[8][4] = {};

    // ---- staging bases: chunk = 8 rows x 64 cols (1KB) per async16;
    // row = R + (lane>>3); global k-seg XOR-swizzled (row&7 = lane>>3) ----
    const int sseg = (lane & 7) ^ (lane >> 3);
    const unsigned short* AsrcB = A + ((size_t)(bm * 256) + (lane >> 3)) * KDIM + sseg * 8;
    const unsigned short* BsrcB = Bt + ((size_t)(bn * 256) + (lane >> 3)) * KDIM + sseg * 8;

    // per-wave chunk rows (coverage: A rows wid*8+{0,64,128,192};
    // B rows: waves*4 chunks of 8 spanning [0,256))
    const int aR0 = wid * 8,       aR1 = 64 + wid * 8;
    const int aR2 = 128 + wid * 8, aR3 = 192 + wid * 8;
    const int bB  = (wid >> 1) * 64 + (wid & 1) * 16;   // base of wave's B region
    const int bR0 = bB, bR1 = bB + 8, bR2 = bB + 32, bR3 = bB + 40;

    auto stA = [&](int R, int k, int buf) {
        async16(AsrcB + (size_t)R * KDIM + k, Als + buf + R * 64);
    };
    auto stB = [&](int R, int k, int buf) {
        async16(BsrcB + (size_t)R * KDIM + k, Bls + buf + R * 64);
    };
    auto stage_all = [&](int k, int buf) {
        stA(aR0, k, buf); stA(aR1, k, buf); stA(aR2, k, buf); stA(aR3, k, buf);
        stB(bR0, k, buf); stB(bR1, k, buf); stB(bR2, k, buf); stB(bR3, k, buf);
    };

    // ---- fragment addressing (16x16x32, conflict-free) ----
    const int frow = lane & 15;
    const int r7   = lane & 7;
    const int ph0  = ((lane >> 4) ^ r7) * 8;   // k-seg s=0 (phys, elements)
    const int ph1v = ph0 ^ 32;                 // k-seg s=1 (s*4 flips bit 2)
    int aOff[8], bOff[4];
    #pragma unroll
    for (int mi = 0; mi < 8; ++mi) aOff[mi] = (wr * 128 + mi * 16 + frow) * 64;
    #pragma unroll
    for (int ni = 0; ni < 4; ++ni) bOff[ni] = (wc * 64 + ni * 16 + frow) * 64;

    // ---- prologue: stage K-tile 0 into buffer 0, exact drain, sync ----
    stage_all(0, 0);
    WAIT_VM0();
    bar();

    bf16x8 aL[4][2], aH[4][2], bL[2][2], bH[2][2];

    for (int t = 0; t < 16; ++t) {
        const int cur = (t & 1) * TILE;
        const int nxt = cur ^ TILE;
        const int k1  = t * 64 + 64;       // next tile's k offset
        const bool pf = (t < 15);

        // ---- issue next tile's staging FIRST (max cover to tile-end vm0)
        if (pf) stage_all(k1, nxt);

        // ---- all fragment reads (compiler handles lgkm precisely) ----
        #pragma unroll
        for (int mi = 0; mi < 4; ++mi) {
            aL[mi][0] = *(const bf16x8*)&Als[cur + aOff[mi] + ph0];
            aL[mi][1] = *(const bf16x8*)&Als[cur + aOff[mi] + ph1v];
        }
        #pragma unroll
        for (int ni = 0; ni < 2; ++ni) {
            bL[ni][0] = *(const bf16x8*)&Bls[cur + bOff[ni] + ph0];
            bL[ni][1] = *(const bf16x8*)&Bls[cur + bOff[ni] + ph1v];
            bH[ni][0] = *(const bf16x8*)&Bls[cur + bOff[ni + 2] + ph0];
            bH[ni][1] = *(const bf16x8*)&Bls[cur + bOff[ni + 2] + ph1v];
        }
        #pragma unroll
        for (int mi = 0; mi < 4; ++mi) {
            aH[mi][0] = *(const bf16x8*)&Als[cur + aOff[mi + 4] + ph0];
            aH[mi][1] = *(const bf16x8*)&Als[cur + aOff[mi + 4] + ph1v];
        }

        // ---- 64 MFMA (4 quadrants); compiler interleaves with reads ----
        __builtin_amdgcn_s_setprio(1);
        #pragma unroll
        for (int mi = 0; mi < 4; ++mi)
            #pragma unroll
            for (int ni = 0; ni < 2; ++ni) {
                acc[mi][ni] = MFMA(aL[mi][0], bL[ni][0], acc[mi][ni]);
                acc[mi][ni] = MFMA(aL[mi][1], bL[ni][1], acc[mi][ni]);
            }
        #pragma unroll
        for (int mi = 0; mi < 4; ++mi)
            #pragma unroll
            for (int ni = 0; ni < 2; ++ni) {
                acc[mi][ni + 2] = MFMA(aL[mi][0], bH[ni][0], acc[mi][ni + 2]);
                acc[mi][ni + 2] = MFMA(aL[mi][1], bH[ni][1], acc[mi][ni + 2]);
            }
        #pragma unroll
        for (int mi = 0; mi < 4; ++mi)
            #pragma unroll
            for (int ni = 0; ni < 2; ++ni) {
                acc[mi + 4][ni + 2] = MFMA(aH[mi][0], bH[ni][0], acc[mi + 4][ni + 2]);
                acc[mi + 4][ni + 2] = MFMA(aH[mi][1], bH[ni][1], acc[mi + 4][ni + 2]);
            }
        #pragma unroll
        for (int mi = 0; mi < 4; ++mi)
            #pragma unroll
            for (int ni = 0; ni < 2; ++ni) {
                acc[mi + 4][ni] = MFMA(aH[mi][0], bL[ni][0], acc[mi + 4][ni]);
                acc[mi + 4][ni] = MFMA(aH[mi][1], bL[ni][1], acc[mi + 4][ni]);
            }
        __builtin_amdgcn_s_setprio(0);

        WAIT_VM0();   // exact full drain: tile t+1 staged (issued at tile top)
        bar();
    }

    // ---- epilogue: D[row=(lane>>4)*4+r][col=lane&15]
    const int rb = wr * 128 + (lane >> 4) * 4;
    const int cb = wc * 64 + (lane & 15);
    float bv[4];
    #pragma unroll
    for (int ni = 0; ni < 4; ++ni) bv[ni] = bias[bn * 256 + cb + ni * 16];
    #pragma unroll
    for (int mi = 0; mi < 8; ++mi) {
        #pragma unroll
        for (int r = 0; r < 4; ++r) {
            size_t grow = (size_t)(bm * 256 + rb + mi * 16 + r) * NDIM;
            #pragma unroll
            for (int ni = 0; ni < 4; ++ni)
                C[grow + bn * 256 + cb + ni * 16] = f2bf(acc[mi][ni][r] + bv[ni]);
        }
    }
}

// ---------------------------------------------------------------------------
// fused LN(hi)+LN(hh)+gates+LN(cell)+outputs. TWO rows per block:
// sub = tid>>7 selects row, t = tid&127 covers 8 cols per gate (16B loads).
// ---------------------------------------------------------------------------
__global__ __launch_bounds__(256) void ln_gates(
    const unsigned short* __restrict__ hi_pre, const unsigned short* __restrict__ hh_pre,
    const float* __restrict__ c_prev,
    const float* __restrict__ g1, const float* __restrict__ be1,
    const float* __restrict__ g2, const float* __restrict__ be2,
    const float* __restrict__ gc, const float* __restrict__ bec,
    float* __restrict__ h_out, float* __restrict__ c_out)
{
    __shared__ float sm[16];
    const int tid = threadIdx.x;
    const int sub = tid >> 7, t = tid & 127;
    const int wv = tid >> 6, lane = tid & 63;
    const int row = blockIdx.x * 2 + sub;
    const unsigned short* hir = hi_pre + (size_t)row * NDIM;
    const unsigned short* hhr = hh_pre + (size_t)row * NDIM;

    u16x8 vi[4], vh[4];
    float s1 = 0.f, ss1 = 0.f, s2 = 0.f, ss2 = 0.f;
    #pragma unroll
    for (int q = 0; q < 4; ++q) {
        int col = q * 1024 + t * 8;
        vi[q] = *(const u16x8*)(hir + col);
        vh[q] = *(const u16x8*)(hhr + col);
        #pragma unroll
        for (int j = 0; j < 8; ++j) {
            float a = bf2f(vi[q][j]), b = bf2f(vh[q][j]);
            s1 += a; ss1 += a * a; s2 += b; ss2 += b * b;
        }
    }
    #pragma unroll
    for (int off = 32; off > 0; off >>= 1) {
        s1 += __shfl_down(s1, off, 64);
        ss1 += __shfl_down(ss1, off, 64);
        s2 += __shfl_down(s2, off, 64);
        ss2 += __shfl_down(ss2, off, 64);
    }
    if (lane == 0) {
        sm[wv * 4 + 0] = s1; sm[wv * 4 + 1] = ss1;
        sm[wv * 4 + 2] = s2; sm[wv * 4 + 3] = ss2;
    }
    __syncthreads();
    const int base = sub * 8;
    float R1 = sm[base + 0] + sm[base + 4];
    float Q1 = sm[base + 1] + sm[base + 5];
    float R2 = sm[base + 2] + sm[base + 6];
    float Q2 = sm[base + 3] + sm[base + 7];

    const float n1 = (float)NDIM;
    float m1 = R1 / n1;
    float v1 = (Q1 - n1 * m1 * m1) / (n1 - 1.f);
    float r1 = 1.0f / (sqrtf(fmaxf(v1, 0.f)) + EPSV);
    float m2 = R2 / n1;
    float v2 = (Q2 - n1 * m2 * m2) / (n1 - 1.f);
    float r2 = 1.0f / (sqrtf(fmaxf(v2, 0.f)) + EPSV);

    float gate[4][8];
    #pragma unroll
    for (int q = 0; q < 4; ++q) {
        int col = q * 1024 + t * 8;
        float4 G1a = *(const float4*)(g1 + col),  G1b = *(const float4*)(g1 + col + 4);
        float4 B1a = *(const float4*)(be1 + col), B1b = *(const float4*)(be1 + col + 4);
        float4 G2a = *(const float4*)(g2 + col),  G2b = *(const float4*)(g2 + col + 4);
        float4 B2a = *(const float4*)(be2 + col), B2b = *(const float4*)(be2 + col + 4);
        float G1[8] = {G1a.x, G1a.y, G1a.z, G1a.w, G1b.x, G1b.y, G1b.z, G1b.w};
        float B1[8] = {B1a.x, B1a.y, B1a.z, B1a.w, B1b.x, B1b.y, B1b.z, B1b.w};
        float G2[8] = {G2a.x, G2a.y, G2a.z, G2a.w, G2b.x, G2b.y, G2b.z, G2b.w};
        float B2[8] = {B2a.x, B2a.y, B2a.z, B2a.w, B2b.x, B2b.y, B2b.z, B2b.w};
        #pragma unroll
        for (int j = 0; j < 8; ++j)
            gate[q][j] = G1[j] * (bf2f(vi[q][j]) - m1) * r1 + B1[j]
                       + G2[j] * (bf2f(vh[q][j]) - m2) * r2 + B2[j];
    }

    float4 cpa = *(const float4*)(c_prev + (size_t)row * 1024 + t * 8);
    float4 cpb = *(const float4*)(c_prev + (size_t)row * 1024 + t * 8 + 4);
    float cpv[8] = {cpa.x, cpa.y, cpa.z, cpa.w, cpb.x, cpb.y, cpb.z, cpb.w};
    float a[8];
    float s3 = 0.f, ss3 = 0.f;
    #pragma unroll
    for (int j = 0; j < 8; ++j) {
        a[j] = cpv[j] * sigm(gate[1][j] + 1.0f) + ftanh(gate[2][j]) * sigm(gate[0][j]);
        s3 += a[j]; ss3 += a[j] * a[j];
    }
    #pragma unroll
    for (int off = 32; off > 0; off >>= 1) {
        s3 += __shfl_down(s3, off, 64);
        ss3 += __shfl_down(ss3, off, 64);
    }
    __syncthreads();   // sm reuse
    if (lane == 0) { sm[wv * 2 + 0] = s3; sm[wv * 2 + 1] = ss3; }
    __syncthreads();
    const int b2 = sub * 4;
    float R3 = sm[b2 + 0] + sm[b2 + 2];
    float Q3 = sm[b2 + 1] + sm[b2 + 3];
    const float n3 = 1024.f;
    float m3 = R3 / n3;
    float v3 = (Q3 - n3 * m3 * m3) / (n3 - 1.f);
    float r3 = 1.0f / (sqrtf(fmaxf(v3, 0.f)) + EPSV);

    int colh = t * 8;
    float4 GCa = *(const float4*)(gc + colh),  GCb = *(const float4*)(gc + colh + 4);
    float4 BCa = *(const float4*)(bec + colh), BCb = *(const float4*)(bec + colh + 4);
    float GC[8] = {GCa.x, GCa.y, GCa.z, GCa.w, GCb.x, GCb.y, GCb.z, GCb.w};
    float BC[8] = {BCa.x, BCa.y, BCa.z, BCa.w, BCb.x, BCb.y, BCb.z, BCb.w};
    float cj[8], hj[8];
    #pragma unroll
    for (int j = 0; j < 8; ++j) {
        cj[j] = GC[j] * (a[j] - m3) * r3 + BC[j];
        hj[j] = sigm(gate[3][j]) * ftanh(cj[j]);
    }
    float4 hva = {hj[0], hj[1], hj[2], hj[3]}, hvb = {hj[4], hj[5], hj[6], hj[7]};
    float4 cva = {cj[0], cj[1], cj[2], cj[3]}, cvb = {cj[4], cj[5], cj[6], cj[7]};
    *(float4*)(h_out + (size_t)row * 1024 + colh) = hva;
    *(float4*)(h_out + (size_t)row * 1024 + colh + 4) = hvb;
    *(float4*)(c_out + (size_t)row * 1024 + colh) = cva;
    *(float4*)(c_out + (size_t)row * 1024 + colh + 4) = cvb;
}

// ---------------------------------------------------------------------------
extern "C" void kernel_launch(void* const* d_in, const int* in_sizes, int n_in,
                              void* d_out, int out_size, void* d_ws, size_t ws_size,
                              hipStream_t stream) {
    const float* input  = (const float*)d_in[0];
    const float* h_prev = (const float*)d_in[1];
    const float* c_prev = (const float*)d_in[2];
    const float* w_i2h  = (const float*)d_in[3];
    const float* b_i2h  = (const float*)d_in[4];
    const float* w_h2h  = (const float*)d_in[5];
    const float* b_h2h  = (const float*)d_in[6];
    const float* g_i2h  = (const float*)d_in[7];
    const float* be_i2h = (const float*)d_in[8];
    const float* g_h2h  = (const float*)d_in[9];
    const float* be_h2h = (const float*)d_in[10];
    const float* g_c    = (const float*)d_in[11];
    const float* be_c   = (const float*)d_in[12];

    const size_t MK = (size_t)BDIM * KDIM;       // 4M
    const size_t MN = (size_t)BDIM * NDIM;       // 16M

    unsigned short* inA    = (unsigned short*)d_ws;
    unsigned short* inH    = inA + MK;
    unsigned short* w1T    = inH + MK;           // [N][K]
    unsigned short* w2T    = w1T + MK;
    unsigned short* hi_pre = w2T + MK;           // [B][4H] bf16
    unsigned short* hh_pre = hi_pre + MN;        // total 96 MB

    float* h_out = (float*)d_out;
    float* c_out = h_out + (size_t)BDIM * 1024;

    prep<<<dim3(2048, 1, 4), 256, 0, stream>>>(
        input, inA, h_prev, inH, w_i2h, w1T, w_h2h, w2T);

    gemm_bias_bf16<<<dim3(256, 1, 2), 512, 0, stream>>>(
        inA, w1T, b_i2h, hi_pre, inH, w2T, b_h2h, hh_pre);

    ln_gates<<<2048, 256, 0, stream>>>(
        hi_pre, hh_pre, c_prev, g_i2h, be_i2h, g_h2h, be_h2h, g_c, be_c, h_out, c_out);
}

// Round 10
// 239.498 us; speedup vs baseline: 1.0406x; 1.0369x over previous
//
#include <hip/hip_runtime.h>
#include <hip/hip_bf16.h>
#include <stdint.h>

// ---------------------------------------------------------------------------
// LayerNormLSTMCell: B=4096, I=H=1024, 4H=4096
//  hi = LN(input @ w_i2h + b_i2h; g_i2h, be_i2h)        [B,4H]
//  hh = LN(h_prev @ w_h2h + b_h2h; g_h2h, be_h2h)       [B,4H]
//  i,f,u,o = split(hi+hh, 4)
//  c = LN(c_prev*sigm(f+1) + tanh(u)*sigm(i); g_c,be_c) [B,H]
//  h = sigm(o)*tanh(c)
// LN: mean, UNBIASED std (ddof=1), divide by (std + 1e-6)
// ---------------------------------------------------------------------------

#define BDIM 4096
#define KDIM 1024
#define NDIM 4096
#define EPSV 1e-6f

typedef float f32x4 __attribute__((ext_vector_type(4)));
typedef __bf16 bf16x8 __attribute__((ext_vector_type(8)));
typedef unsigned short u16x8 __attribute__((ext_vector_type(8)));

__device__ inline unsigned short f2bf(float f) {
    unsigned u = __builtin_bit_cast(unsigned, f);
    u += 0x7FFFu + ((u >> 16) & 1u);   // round-to-nearest-even
    return (unsigned short)(u >> 16);
}
__device__ inline float bf2f(unsigned short u) {
    return __builtin_bit_cast(float, (unsigned)u << 16);
}
__device__ inline float sigm(float x) {
    return 1.0f / (1.0f + __expf(-x));
}
__device__ inline float ftanh(float x) {
    return 1.0f - 2.0f / (__expf(2.0f * x) + 1.0f);
}

// async global->LDS, 16B per lane. lds ptr must be wave-uniform.
__device__ inline void async16(const unsigned short* g, unsigned short* lds) {
    __builtin_amdgcn_global_load_lds(
        (const __attribute__((address_space(1))) void*)g,
        (__attribute__((address_space(3))) void*)lds,
        16, 0, 0);
}

// raw workgroup barrier with compiler memory fence (does NOT drain vmcnt).
__device__ inline void bar() {
    asm volatile("" ::: "memory");
    __builtin_amdgcn_s_barrier();
    asm volatile("" ::: "memory");
}
#define WAIT_LGKM0() asm volatile("s_waitcnt lgkmcnt(0)" ::: "memory")
#define WAIT_VM(N)   asm volatile("s_waitcnt vmcnt(" #N ")" ::: "memory")
#define MFMA(a, b, c) __builtin_amdgcn_mfma_f32_16x16x32_bf16((a), (b), (c), 0, 0, 0)

// ---------------------------------------------------------------------------
// prep: z=0/1 cast input/h_prev f32->bf16 (8 elem/thread, 16B stores)
//       z=2/3 transpose+cast w f32 [1024][4096] -> bf16 [4096][1024]
// ---------------------------------------------------------------------------
__global__ __launch_bounds__(256) void prep(
    const float* __restrict__ in0, unsigned short* __restrict__ o0,
    const float* __restrict__ in1, unsigned short* __restrict__ o1,
    const float* __restrict__ w0, unsigned short* __restrict__ w0T,
    const float* __restrict__ w1, unsigned short* __restrict__ w1T)
{
    __shared__ float tile[64][65];
    const int z = blockIdx.z, tid = threadIdx.x;
    if (z < 2) {
        const float* src = z ? in1 : in0;
        unsigned short* dst = z ? o1 : o0;
        int i = (blockIdx.x * 256 + tid) * 8;
        float4 a = *(const float4*)(src + i);
        float4 b = *(const float4*)(src + i + 4);
        u16x8 v;
        v[0] = f2bf(a.x); v[1] = f2bf(a.y); v[2] = f2bf(a.z); v[3] = f2bf(a.w);
        v[4] = f2bf(b.x); v[5] = f2bf(b.y); v[6] = f2bf(b.z); v[7] = f2bf(b.w);
        *(u16x8*)(dst + i) = v;
        return;
    }
    const int bx = blockIdx.x;
    if (bx >= (NDIM / 64) * (KDIM / 64)) return;
    const float* src = (z == 3) ? w1 : w0;
    unsigned short* dst = (z == 3) ? w1T : w0T;
    const int c0 = (bx & (NDIM / 64 - 1)) * 64;   // col in [0,4096)
    const int r0 = (bx >> 6) * 64;                // row in [0,1024)
    const int tx = tid & 63, ty = tid >> 6;       // 64 x 4
    #pragma unroll
    for (int i = 0; i < 64; i += 4)
        tile[ty + i][tx] = src[(size_t)(r0 + ty + i) * NDIM + c0 + tx];
    __syncthreads();
    #pragma unroll
    for (int p = 0; p < 2; ++p) {
        int c = p * 32 + (tid >> 3);
        int rs = (tid & 7) * 8;
        u16x8 v;
        #pragma unroll
        for (int j = 0; j < 8; ++j) v[j] = f2bf(tile[rs + j][c]);
        *(u16x8*)(dst + (size_t)(c0 + c) * KDIM + r0 + rs) = v;
    }
}

// ---------------------------------------------------------------------------
// GEMM: C[m][n] = sum_k A[m][k] * Bt[n][k] + bias[n]   (bf16 in, bf16 out)
// M=4096 N=4096 K=1024.
//
// R9: CONTROLLED EXPERIMENT on counted vmcnt. Evidence so far:
//   counted-spread conveyor (R4, no swizzle)        75.4us  PASSED (once)
//   counted-spread conveyor + swizzle (R6)          82.2us  FAILED replay
//   full-drain variants (R7 burst, R8 minimal-sync) 81.7-82.7us PASS
// R7/R8 proved sync-structure-invariance of the ~830-840 TF plateau =
// m233's "2-phase class" finding; m218 isolated counted-vs-drain0 as THE
// lever (+38-73%). R9 = R6's exact kernel with ONLY the ledger changed
// (one-variable A/B), simplified + one notch more conservative:
//   P1-end: vmcnt(4)  drains G2(t)+G3(t) together   [guards P2 AND P3 reads]
//           (t==15: vmcnt(0) -- tail full drain)
//   P4-end: vmcnt(4)  drains G1(t+1)                [guards P1(t+1) reads]
// Never 0 mid-loop. Ledger stepped: entering tile t outst=4 [G2,G3(t)];
// P1 +G1(t+1)[4] -> 8; vm(4) -> 4; P2 +G2(t+1)[2] -> 6; P3 +G3(t+1)[2] -> 8;
// P4 vm(4) -> 4 = entry invariant. Prologue vm(0) primes t=0 path.
// Pre-committed read: PASS -> counted rehabilitated, deepen next round;
// FAIL -> counted-vmcnt class unsound here, revert to R8 permanently.
//
// Staging groups (unchanged from R4/R6): G1 = A rows [0,64)+[128,192) +
// B rows wc*64+[0,32) [4 ld/wave, issued P1]; G2 = B rows wc*64+[32,64)
// [2 ld/wave, P2]; G3 = A rows [64,128)+[192,256) [2 ld/wave, P3].
//
// XCD-bijective swizzle kept (validated: FETCH 74->49-51MB = L2 floor).
// Data path: staging rows XOR-swizzle global k-seg (sseg=(lane&7)^(row&7)),
// LDS linear; fragment reads phys seg=(s*4+q)^r7 (ZERO bank conflicts,
// verified R2/R4/R6/R7/R8); C/D D[row=(lane>>4)*4+r][col=lane&15].
// ---------------------------------------------------------------------------
__global__ __launch_bounds__(512, 2) void gemm_bias_bf16(
    const unsigned short* __restrict__ A0, const unsigned short* __restrict__ B0,
    const float* __restrict__ bias0, unsigned short* __restrict__ C0,
    const unsigned short* __restrict__ A1, const unsigned short* __restrict__ B1,
    const float* __restrict__ bias1, unsigned short* __restrict__ C1)
{
    const unsigned short* A  = blockIdx.z ? A1 : A0;
    const unsigned short* Bt = blockIdx.z ? B1 : B0;
    const float* bias        = blockIdx.z ? bias1 : bias0;
    unsigned short* C        = blockIdx.z ? C1 : C0;

    __shared__ __align__(16) unsigned short Als[2 * 256 * 64];   // 64 KB
    __shared__ __align__(16) unsigned short Bls[2 * 256 * 64];   // 64 KB
    const int TILE = 256 * 64;

    const int tid  = threadIdx.x;
    const int wid  = tid >> 6;
    const int lane = tid & 63;

    // ---- XCD-bijective swizzle: b%8 ~ XCD; each XCD owns a 4bm x 8bn
    // chunk (32 blocks, co-resident at 1 blk/CU) ----
    const int b   = blockIdx.x;          // 0..255
    const int xcd = b & 7, idx = b >> 3; // idx 0..31
    const int bm  = (xcd >> 1) * 4 + (idx & 3);    // 0..15
    const int bn  = (xcd & 1) * 8 + (idx >> 2);    // 0..15

    const int wr = wid >> 2;        // wave row: rows wr*128
    const int wc = wid & 3;         // wave col: cols wc*64

    f32x4 acc[8][4] = {};

    // ---- staging bases: chunk = 8 rows x 64 cols (1KB) per async16;
    // row = R + (lane>>3); global k-seg XOR-swizzled (row&7 = lane>>3) ----
    const int sseg = (lane & 7) ^ (lane >> 3);
    const unsigned short* AsrcB = A + ((size_t)(bm * 256) + (lane >> 3)) * KDIM + sseg * 8;
    const unsigned short* BsrcB = Bt + ((size_t)(bn * 256) + (lane >> 3)) * KDIM + sseg * 8;

    // per-wave chunk rows for each group
    const int aG1r0 = wid * 8,        aG1r1 = 128 + wid * 8;   // G1: A
    const int g1b0  = (wid >> 1) * 64 + (wid & 1) * 16;        // G1: B
    const int g1b1  = g1b0 + 8;
    const int g2b0  = g1b0 + 32,      g2b1 = g1b0 + 40;        // G2: B
    const int aG3r0 = 64 + wid * 8,   aG3r1 = 192 + wid * 8;   // G3: A

    auto stA = [&](int R, int k, int buf) {
        async16(AsrcB + (size_t)R * KDIM + k, Als + buf + R * 64);
    };
    auto stB = [&](int R, int k, int buf) {
        async16(BsrcB + (size_t)R * KDIM + k, Bls + buf + R * 64);
    };

    // ---- fragment addressing (16x16x32, conflict-free) ----
    const int frow = lane & 15;
    const int r7   = lane & 7;
    const int ph0  = ((lane >> 4) ^ r7) * 8;   // k-seg s=0 (phys, elements)
    const int ph1v = ph0 ^ 32;                 // k-seg s=1 (s*4 flips bit 2)
    int aOff[8], bOff[4];
    #pragma unroll
    for (int mi = 0; mi < 8; ++mi) aOff[mi] = (wr * 128 + mi * 16 + frow) * 64;
    #pragma unroll
    for (int ni = 0; ni < 4; ++ni) bOff[ni] = (wc * 64 + ni * 16 + frow) * 64;

    // ---- prologue: stage K-tile 0 into buffer 0 (group order), drain ----
    stA(aG1r0, 0, 0); stA(aG1r1, 0, 0); stB(g1b0, 0, 0); stB(g1b1, 0, 0);
    stB(g2b0, 0, 0);  stB(g2b1, 0, 0);
    stA(aG3r0, 0, 0); stA(aG3r1, 0, 0);
    WAIT_VM(0);
    bar();

    bf16x8 aL[4][2], aH[4][2], bL[2][2], bH[2][2];

    for (int t = 0; t < 16; ++t) {
        const int cur = (t & 1) * TILE;
        const int nxt = cur ^ TILE;
        const int k1  = t * 64 + 64;       // next tile's k offset
        const bool pf = (t < 15);

        // ===== phase 1: read A-low + B-low (G1(t)); issue G1(t+1) =====
        #pragma unroll
        for (int mi = 0; mi < 4; ++mi) {
            aL[mi][0] = *(const bf16x8*)&Als[cur + aOff[mi] + ph0];
            aL[mi][1] = *(const bf16x8*)&Als[cur + aOff[mi] + ph1v];
        }
        #pragma unroll
        for (int ni = 0; ni < 2; ++ni) {
            bL[ni][0] = *(const bf16x8*)&Bls[cur + bOff[ni] + ph0];
            bL[ni][1] = *(const bf16x8*)&Bls[cur + bOff[ni] + ph1v];
        }
        if (pf) {
            stA(aG1r0, k1, nxt); stA(aG1r1, k1, nxt);
            stB(g1b0, k1, nxt);  stB(g1b1, k1, nxt);
        }
        bar();
        WAIT_LGKM0();
        __builtin_amdgcn_s_setprio(1);
        #pragma unroll
        for (int mi = 0; mi < 4; ++mi)
            #pragma unroll
            for (int ni = 0; ni < 2; ++ni) {
                acc[mi][ni] = MFMA(aL[mi][0], bL[ni][0], acc[mi][ni]);
                acc[mi][ni] = MFMA(aL[mi][1], bL[ni][1], acc[mi][ni]);
            }
        __builtin_amdgcn_s_setprio(0);
        if (pf) { WAIT_VM(4); } else { WAIT_VM(0); }   // drain G2(t)+G3(t)
        bar();

        // ===== phase 2: read B-high (G2(t)); issue G2(t+1) =====
        #pragma unroll
        for (int ni = 0; ni < 2; ++ni) {
            bH[ni][0] = *(const bf16x8*)&Bls[cur + bOff[ni + 2] + ph0];
            bH[ni][1] = *(const bf16x8*)&Bls[cur + bOff[ni + 2] + ph1v];
        }
        if (pf) { stB(g2b0, k1, nxt); stB(g2b1, k1, nxt); }
        bar();
        WAIT_LGKM0();
        __builtin_amdgcn_s_setprio(1);
        #pragma unroll
        for (int mi = 0; mi < 4; ++mi)
            #pragma unroll
            for (int ni = 0; ni < 2; ++ni) {
                acc[mi][ni + 2] = MFMA(aL[mi][0], bH[ni][0], acc[mi][ni + 2]);
                acc[mi][ni + 2] = MFMA(aL[mi][1], bH[ni][1], acc[mi][ni + 2]);
            }
        __builtin_amdgcn_s_setprio(0);
        bar();

        // ===== phase 3: read A-high (G3(t), drained at P1-end); issue G3(t+1) =====
        #pragma unroll
        for (int mi = 0; mi < 4; ++mi) {
            aH[mi][0] = *(const bf16x8*)&Als[cur + aOff[mi + 4] + ph0];
            aH[mi][1] = *(const bf16x8*)&Als[cur + aOff[mi + 4] + ph1v];
        }
        if (pf) { stA(aG3r0, k1, nxt); stA(aG3r1, k1, nxt); }
        bar();
        WAIT_LGKM0();
        __builtin_amdgcn_s_setprio(1);
        #pragma unroll
        for (int mi = 0; mi < 4; ++mi)
            #pragma unroll
            for (int ni = 0; ni < 2; ++ni) {
                acc[mi + 4][ni + 2] = MFMA(aH[mi][0], bH[ni][0], acc[mi + 4][ni + 2]);
                acc[mi + 4][ni + 2] = MFMA(aH[mi][1], bH[ni][1], acc[mi + 4][ni + 2]);
            }
        __builtin_amdgcn_s_setprio(0);
        bar();

        // ===== phase 4: A-high x B-low; counted guard for G1(t+1) =====
        __builtin_amdgcn_s_setprio(1);
        #pragma unroll
        for (int mi = 0; mi < 4; ++mi)
            #pragma unroll
            for (int ni = 0; ni < 2; ++ni) {
                acc[mi + 4][ni] = MFMA(aH[mi][0], bL[ni][0], acc[mi + 4][ni]);
                acc[mi + 4][ni] = MFMA(aH[mi][1], bL[ni][1], acc[mi + 4][ni]);
            }
        __builtin_amdgcn_s_setprio(0);
        if (pf) { WAIT_VM(4); }     // drain G1(t+1); never 0 mid-loop
        bar();
    }

    // ---- epilogue: D[row=(lane>>4)*4+r][col=lane&15]
    const int rb = wr * 128 + (lane >> 4) * 4;
    const int cb = wc * 64 + (lane & 15);
    float bv[4];
    #pragma unroll
    for (int ni = 0; ni < 4; ++ni) bv[ni] = bias[bn * 256 + cb + ni * 16];
    #pragma unroll
    for (int mi = 0; mi < 8; ++mi) {
        #pragma unroll
        for (int r = 0; r < 4; ++r) {
            size_t grow = (size_t)(bm * 256 + rb + mi * 16 + r) * NDIM;
            #pragma unroll
            for (int ni = 0; ni < 4; ++ni)
                C[grow + bn * 256 + cb + ni * 16] = f2bf(acc[mi][ni][r] + bv[ni]);
        }
    }
}

// ---------------------------------------------------------------------------
// fused LN(hi)+LN(hh)+gates+LN(cell)+outputs. TWO rows per block:
// sub = tid>>7 selects row, t = tid&127 covers 8 cols per gate (16B loads).
// ---------------------------------------------------------------------------
__global__ __launch_bounds__(256) void ln_gates(
    const unsigned short* __restrict__ hi_pre, const unsigned short* __restrict__ hh_pre,
    const float* __restrict__ c_prev,
    const float* __restrict__ g1, const float* __restrict__ be1,
    const float* __restrict__ g2, const float* __restrict__ be2,
    const float* __restrict__ gc, const float* __restrict__ bec,
    float* __restrict__ h_out, float* __restrict__ c_out)
{
    __shared__ float sm[16];
    const int tid = threadIdx.x;
    const int sub = tid >> 7, t = tid & 127;
    const int wv = tid >> 6, lane = tid & 63;
    const int row = blockIdx.x * 2 + sub;
    const unsigned short* hir = hi_pre + (size_t)row * NDIM;
    const unsigned short* hhr = hh_pre + (size_t)row * NDIM;

    u16x8 vi[4], vh[4];
    float s1 = 0.f, ss1 = 0.f, s2 = 0.f, ss2 = 0.f;
    #pragma unroll
    for (int q = 0; q < 4; ++q) {
        int col = q * 1024 + t * 8;
        vi[q] = *(const u16x8*)(hir + col);
        vh[q] = *(const u16x8*)(hhr + col);
        #pragma unroll
        for (int j = 0; j < 8; ++j) {
            float a = bf2f(vi[q][j]), b = bf2f(vh[q][j]);
            s1 += a; ss1 += a * a; s2 += b; ss2 += b * b;
        }
    }
    #pragma unroll
    for (int off = 32; off > 0; off >>= 1) {
        s1 += __shfl_down(s1, off, 64);
        ss1 += __shfl_down(ss1, off, 64);
        s2 += __shfl_down(s2, off, 64);
        ss2 += __shfl_down(ss2, off, 64);
    }
    if (lane == 0) {
        sm[wv * 4 + 0] = s1; sm[wv * 4 + 1] = ss1;
        sm[wv * 4 + 2] = s2; sm[wv * 4 + 3] = ss2;
    }
    __syncthreads();
    const int base = sub * 8;
    float R1 = sm[base + 0] + sm[base + 4];
    float Q1 = sm[base + 1] + sm[base + 5];
    float R2 = sm[base + 2] + sm[base + 6];
    float Q2 = sm[base + 3] + sm[base + 7];

    const float n1 = (float)NDIM;
    float m1 = R1 / n1;
    float v1 = (Q1 - n1 * m1 * m1) / (n1 - 1.f);
    float r1 = 1.0f / (sqrtf(fmaxf(v1, 0.f)) + EPSV);
    float m2 = R2 / n1;
    float v2 = (Q2 - n1 * m2 * m2) / (n1 - 1.f);
    float r2 = 1.0f / (sqrtf(fmaxf(v2, 0.f)) + EPSV);

    float gate[4][8];
    #pragma unroll
    for (int q = 0; q < 4; ++q) {
        int col = q * 1024 + t * 8;
        float4 G1a = *(const float4*)(g1 + col),  G1b = *(const float4*)(g1 + col + 4);
        float4 B1a = *(const float4*)(be1 + col), B1b = *(const float4*)(be1 + col + 4);
        float4 G2a = *(const float4*)(g2 + col),  G2b = *(const float4*)(g2 + col + 4);
        float4 B2a = *(const float4*)(be2 + col), B2b = *(const float4*)(be2 + col + 4);
        float G1[8] = {G1a.x, G1a.y, G1a.z, G1a.w, G1b.x, G1b.y, G1b.z, G1b.w};
        float B1[8] = {B1a.x, B1a.y, B1a.z, B1a.w, B1b.x, B1b.y, B1b.z, B1b.w};
        float G2[8] = {G2a.x, G2a.y, G2a.z, G2a.w, G2b.x, G2b.y, G2b.z, G2b.w};
        float B2[8] = {B2a.x, B2a.y, B2a.z, B2a.w, B2b.x, B2b.y, B2b.z, B2b.w};
        #pragma unroll
        for (int j = 0; j < 8; ++j)
            gate[q][j] = G1[j] * (bf2f(vi[q][j]) - m1) * r1 + B1[j]
                       + G2[j] * (bf2f(vh[q][j]) - m2) * r2 + B2[j];
    }

    float4 cpa = *(const float4*)(c_prev + (size_t)row * 1024 + t * 8);
    float4 cpb = *(const float4*)(c_prev + (size_t)row * 1024 + t * 8 + 4);
    float cpv[8] = {cpa.x, cpa.y, cpa.z, cpa.w, cpb.x, cpb.y, cpb.z, cpb.w};
    float a[8];
    float s3 = 0.f, ss3 = 0.f;
    #pragma unroll
    for (int j = 0; j < 8; ++j) {
        a[j] = cpv[j] * sigm(gate[1][j] + 1.0f) + ftanh(gate[2][j]) * sigm(gate[0][j]);
        s3 += a[j]; ss3 += a[j] * a[j];
    }
    #pragma unroll
    for (int off = 32; off > 0; off >>= 1) {
        s3 += __shfl_down(s3, off, 64);
        ss3 += __shfl_down(ss3, off, 64);
    }
    __syncthreads();   // sm reuse
    if (lane == 0) { sm[wv * 2 + 0] = s3; sm[wv * 2 + 1] = ss3; }
    __syncthreads();
    const int b2 = sub * 4;
    float R3 = sm[b2 + 0] + sm[b2 + 2];
    float Q3 = sm[b2 + 1] + sm[b2 + 3];
    const float n3 = 1024.f;
    float m3 = R3 / n3;
    float v3 = (Q3 - n3 * m3 * m3) / (n3 - 1.f);
    float r3 = 1.0f / (sqrtf(fmaxf(v3, 0.f)) + EPSV);

    int colh = t * 8;
    float4 GCa = *(const float4*)(gc + colh),  GCb = *(const float4*)(gc + colh + 4);
    float4 BCa = *(const float4*)(bec + colh), BCb = *(const float4*)(bec + colh + 4);
    float GC[8] = {GCa.x, GCa.y, GCa.z, GCa.w, GCb.x, GCb.y, GCb.z, GCb.w};
    float BC[8] = {BCa.x, BCa.y, BCa.z, BCa.w, BCb.x, BCb.y, BCb.z, BCb.w};
    float cj[8], hj[8];
    #pragma unroll
    for (int j = 0; j < 8; ++j) {
        cj[j] = GC[j] * (a[j] - m3) * r3 + BC[j];
        hj[j] = sigm(gate[3][j]) * ftanh(cj[j]);
    }
    float4 hva = {hj[0], hj[1], hj[2], hj[3]}, hvb = {hj[4], hj[5], hj[6], hj[7]};
    float4 cva = {cj[0], cj[1], cj[2], cj[3]}, cvb = {cj[4], cj[5], cj[6], cj[7]};
    *(float4*)(h_out + (size_t)row * 1024 + colh) = hva;
    *(float4*)(h_out + (size_t)row * 1024 + colh + 4) = hvb;
    *(float4*)(c_out + (size_t)row * 1024 + colh) = cva;
    *(float4*)(c_out + (size_t)row * 1024 + colh + 4) = cvb;
}

// ---------------------------------------------------------------------------
extern "C" void kernel_launch(void* const* d_in, const int* in_sizes, int n_in,
                              void* d_out, int out_size, void* d_ws, size_t ws_size,
                              hipStream_t stream) {
    const float* input  = (const float*)d_in[0];
    const float* h_prev = (const float*)d_in[1];
    const float* c_prev = (const float*)d_in[2];
    const float* w_i2h  = (const float*)d_in[3];
    const float* b_i2h  = (const float*)d_in[4];
    const float* w_h2h  = (const float*)d_in[5];
    const float* b_h2h  = (const float*)d_in[6];
    const float* g_i2h  = (const float*)d_in[7];
    const float* be_i2h = (const float*)d_in[8];
    const float* g_h2h  = (const float*)d_in[9];
    const float* be_h2h = (const float*)d_in[10];
    const float* g_c    = (const float*)d_in[11];
    const float* be_c   = (const float*)d_in[12];

    const size_t MK = (size_t)BDIM * KDIM;       // 4M
    const size_t MN = (size_t)BDIM * NDIM;       // 16M

    unsigned short* inA    = (unsigned short*)d_ws;
    unsigned short* inH    = inA + MK;
    unsigned short* w1T    = inH + MK;           // [N][K]
    unsigned short* w2T    = w1T + MK;
    unsigned short* hi_pre = w2T + MK;           // [B][4H] bf16
    unsigned short* hh_pre = hi_pre + MN;        // total 96 MB

    float* h_out = (float*)d_out;
    float* c_out = h_out + (size_t)BDIM * 1024;

    prep<<<dim3(2048, 1, 4), 256, 0, stream>>>(
        input, inA, h_prev, inH, w_i2h, w1T, w_h2h, w2T);

    gemm_bias_bf16<<<dim3(256, 1, 2), 512, 0, stream>>>(
        inA, w1T, b_i2h, hi_pre, inH, w2T, b_h2h, hh_pre);

    ln_gates<<<2048, 256, 0, stream>>>(
        hi_pre, hh_pre, c_prev, g_i2h, be_i2h, g_h2h, be_h2h, g_c, be_c, h_out, c_out);
}